// Round 18
// baseline (1198.917 us; speedup 1.0000x reference)
//
#include <hip/hip_runtime.h>
#include <hip/hip_bf16.h>
#include <cstdint>

typedef __attribute__((ext_vector_type(8))) short short8;
typedef __attribute__((ext_vector_type(4))) float f32x4;
typedef __attribute__((ext_vector_type(4))) unsigned short ushort4v;

#define DEV static __device__ __forceinline__

DEV float bf2f(unsigned short u) {
    union { unsigned int i; float f; } v; v.i = ((unsigned int)u) << 16; return v.f;
}
DEV unsigned short f2bf(float f) {
    union { float f; unsigned int i; } v; v.f = f;
    unsigned int x = v.i;
    unsigned int r = x + 0x7fffu + ((x >> 16) & 1u);
    return (unsigned short)(r >> 16);
}

// ---------------------------------------------------------------------------
// GEMM: C[M,N] = A[M,K] @ Bt[N,K]^T + bias -> bf16.
// BM=256 x BN=128 tile, 512 thr / 8 waves (wr 0..3, wc 0..1); wave = 64x64.
// BK=64 single-buffer (48KB LDS), proven swizzles, full K-unroll + hoisted
// pointers. Halves block count vs 128^2 (A staged once per 128 output cols
// -> per-thread loads 8->6/K-step); grids land exactly: KVQ 1536 = 3.0
// rounds @2 blocks/CU, W1 1024 = 2.0. Epilogue: two 128-row halves through
// the 128x136 transpose buffer. XCD swizzle: 16 M-tiles per XCD.
// EPI 0 (KVQ): elu+1 on cols<512|>=1024; Q -> out2. EPI 2 (W1): relu.
// ---------------------------------------------------------------------------
template<int EPI, int NBY, int LDA, int KT>
__global__ __launch_bounds__(512) void gemm_kernel(
    const unsigned short* __restrict__ A,
    const unsigned short* __restrict__ Bt,
    const float* __restrict__ bias,
    unsigned short* __restrict__ out1, int ldc1,
    unsigned short* __restrict__ out2)
{
    __shared__ unsigned short lds[24576];   // A [0,16384) | B [16384,24576)
    const int t  = threadIdx.x;
    const int w  = t >> 6, l = t & 63;
    const int wr = w >> 1, wc = w & 1;
    const int lr = l & 15, lg = l >> 4;
    const int bid = blockIdx.x;
    const int j8  = bid & 7, s = bid >> 3;
    const int bx  = j8 * 16 + s / NBY;      // 128 M-tiles, 16 per XCD
    const int by  = s % NBY;
    const long tM = (long)bx * 256;
    const long tN = (long)by * 128;

    f32x4 acc[4][4];
#pragma unroll
    for (int i = 0; i < 4; i++)
#pragma unroll
        for (int j = 0; j < 4; j++) acc[i][j] = f32x4{0.f, 0.f, 0.f, 0.f};

    // hoisted staging pointers: A 2048 chunks (4/thread), B 1024 (2/thread)
    const unsigned short* ga[4];
    const unsigned short* gb[2];
#pragma unroll
    for (int j = 0; j < 4; j++) {
        int c = j * 512 + t;
        int row = c >> 3, sc = (c & 7) ^ (row & 7);
        ga[j] = A + (tM + row) * LDA + sc * 8;
    }
#pragma unroll
    for (int j = 0; j < 2; j++) {
        int c = j * 512 + t;
        int row = c >> 3, sc = (c & 7) ^ (row & 7);
        gb[j] = Bt + (tN + row) * (long)KT + sc * 8;
    }

#pragma unroll
    for (int kt = 0; kt < KT; kt += 64) {
#pragma unroll
        for (int j = 0; j < 4; j++)
            __builtin_amdgcn_global_load_lds(
                (const __attribute__((address_space(1))) void*)(ga[j] + kt),
                (__attribute__((address_space(3))) void*)(lds + (j * 512 + (t & ~63)) * 8), 16, 0, 0);
#pragma unroll
        for (int j = 0; j < 2; j++)
            __builtin_amdgcn_global_load_lds(
                (const __attribute__((address_space(1))) void*)(gb[j] + kt),
                (__attribute__((address_space(3))) void*)(lds + 16384 + (j * 512 + (t & ~63)) * 8), 16, 0, 0);
        __syncthreads();
#pragma unroll
        for (int kk = 0; kk < 2; kk++) {
            short8 af[4], bfv[4];
#pragma unroll
            for (int mi = 0; mi < 4; mi++) {
                int r  = wr * 64 + mi * 16 + lr;
                int kc = kk * 4 + lg;
                af[mi] = *(const short8*)&lds[r * 64 + ((kc ^ (r & 7)) << 3)];
            }
#pragma unroll
            for (int ni = 0; ni < 4; ni++) {
                int n  = wc * 64 + ni * 16 + lr;
                int kc = kk * 4 + lg;
                bfv[ni] = *(const short8*)&lds[16384 + n * 64 + ((kc ^ (n & 7)) << 3)];
            }
#pragma unroll
            for (int mi = 0; mi < 4; mi++)
#pragma unroll
                for (int ni = 0; ni < 4; ni++)
                    acc[mi][ni] = __builtin_amdgcn_mfma_f32_16x16x32_bf16(
                        af[mi], bfv[ni], acc[mi][ni], 0, 0, 0);
        }
        __syncthreads();
    }

    float bv[4];
#pragma unroll
    for (int ni = 0; ni < 4; ni++) bv[ni] = bias[tN + wc * 64 + ni * 16 + lr];
    const bool doElu = (EPI == 0) && (tN < 512 || tN >= 1024);

    const bool toQ = (NBY == 12) && (tN >= 1024);
    unsigned short* o = toQ ? out2 : out1;
    const long ldc   = toQ ? 512 : ldc1;
    const long cb    = toQ ? (tN - 1024) : tN;

    // two 128-row halves through the 128x136 transpose buffer (34.8KB < 48KB)
#pragma unroll
    for (int h = 0; h < 2; h++) {
        if ((wr >> 1) == h) {
#pragma unroll
            for (int mi = 0; mi < 4; mi++)
#pragma unroll
                for (int ni = 0; ni < 4; ni++)
#pragma unroll
                    for (int j = 0; j < 4; j++) {
                        float v = acc[mi][ni][j] + bv[ni];
                        if (EPI == 0) { if (doElu) v = (v > 0.f) ? (v + 1.f) : expf(v); }
                        if (EPI == 2) v = fmaxf(v, 0.f);
                        int r = (wr & 1) * 64 + mi * 16 + lg * 4 + j;
                        int c = wc * 64 + ni * 16 + lr;
                        lds[r * 136 + c] = f2bf(v);
                    }
        }
        __syncthreads();
#pragma unroll
        for (int i = 0; i < 4; i++) {        // 128x128 = 2048 chunks / 512 thr
            int q = i * 512 + t;
            int r = q >> 4, cc = q & 15;
            short8 v8 = *(const short8*)&lds[r * 136 + cc * 8];
            *(short8*)&o[(tM + h * 128 + r) * ldc + cb + cc * 8] = v8;
        }
        __syncthreads();
    }
}

// ---------------------------------------------------------------------------
// Fused GEMM + bias + residual + LayerNorm (r17-current). BK=32 dbuf,
// counted-vmcnt loop retained (neutral vs drain; keep as-is). Coalesced bf16
// epilogue via sB bounce. RESBF: residual bf16 vs f32 (lyr0). WRITEOF: final
// LN2 also writes f32 d_out. NO min-wave bound (r8 lesson).
// ---------------------------------------------------------------------------
template<int RESBF, int WRITEOF, int KT>
__global__ __launch_bounds__(512) void gemm_ln_kernel(
    const unsigned short* __restrict__ A, int lda,
    const unsigned short* __restrict__ Bt,   // [512][KT]
    const float* __restrict__ bias,          // [512]
    const void* __restrict__ resp,           // [M][512] f32 or bf16 (RESBF)
    const float* __restrict__ g,
    const float* __restrict__ be,
    float* __restrict__ of,                  // [M][512] f32 (if WRITEOF)
    unsigned short* __restrict__ ob,         // [M][512] bf16
    int unused)
{
    __shared__ unsigned short sA[2][128 * 32];   // 2 x 8 KiB
    __shared__ unsigned short sB[2][512 * 32];   // 2 x 32 KiB
    float* redb  = (float*)&sA[0][0];            // epilogue alias: 4 KiB
    float* statb = redb + 1024;                  // 1 KiB
    unsigned short* bb16 = (unsigned short*)&sB[0][0];  // bounce: 64x512 bf16
    const int t = threadIdx.x, w = t >> 6, l = t & 63, lr = l & 15, lg = l >> 4;
    const int wr = w >> 2, wc = w & 3;
    const long tM = (long)blockIdx.x * 128;

    f32x4 acc[4][8];
#pragma unroll
    for (int i = 0; i < 4; i++)
#pragma unroll
        for (int j = 0; j < 8; j++) acc[i][j] = f32x4{0.f, 0.f, 0.f, 0.f};

    const unsigned short* gA;
    const unsigned short* gB[4];
    unsigned int la, lb[4];
    {
        int c = t, row = c >> 2, sc = (c & 3) ^ ((row >> 1) & 3);
        gA = A + (tM + row) * (long)lda + sc * 8;
        la = (w * 64) * 8;
    }
#pragma unroll
    for (int j = 0; j < 4; j++) {
        int c = j * 512 + t, row = c >> 2, sc = (c & 3) ^ ((row >> 1) & 3);
        gB[j] = Bt + (long)row * KT + sc * 8;
        lb[j] = (j * 512 + w * 64) * 8;
    }

    auto STAGE = [&](int buf, int kt) {
        __builtin_amdgcn_global_load_lds(
            (const __attribute__((address_space(1))) void*)(gA + kt),
            (__attribute__((address_space(3))) void*)(&sA[buf][la]), 16, 0, 0);
#pragma unroll
        for (int j = 0; j < 4; j++)
            __builtin_amdgcn_global_load_lds(
                (const __attribute__((address_space(1))) void*)(gB[j] + kt),
                (__attribute__((address_space(3))) void*)(&sB[buf][lb[j]]), 16, 0, 0);
    };

    auto COMPUTE = [&](int buf) {
        short8 av[4], bw[8];
#pragma unroll
        for (int mi = 0; mi < 4; mi++) {
            int r = wr * 64 + mi * 16 + lr;
            av[mi] = *(const short8*)&sA[buf][r * 32 + ((lg ^ ((r >> 1) & 3)) << 3)];
        }
#pragma unroll
        for (int ni = 0; ni < 8; ni++) {
            int n = wc * 128 + ni * 16 + lr;
            bw[ni] = *(const short8*)&sB[buf][n * 32 + ((lg ^ ((n >> 1) & 3)) << 3)];
        }
#pragma unroll
        for (int mi = 0; mi < 4; mi++)
#pragma unroll
            for (int ni = 0; ni < 8; ni++)
                acc[mi][ni] = __builtin_amdgcn_mfma_f32_16x16x32_bf16(
                    av[mi], bw[ni], acc[mi][ni], 0, 0, 0);
    };

    STAGE(0, 0);
    STAGE(1, 32);
#pragma unroll
    for (int kt = 0; kt < KT; kt += 32) {
        if (kt < KT - 32) asm volatile("s_waitcnt vmcnt(5)" ::: "memory");
        else              asm volatile("s_waitcnt vmcnt(0)" ::: "memory");
        __builtin_amdgcn_s_barrier();
        COMPUTE((kt >> 5) & 1);
        asm volatile("s_waitcnt lgkmcnt(0)" ::: "memory");
        __builtin_amdgcn_s_barrier();
        if (kt + 64 < KT) STAGE((kt >> 5) & 1, kt + 64);
    }

    const float* resf = (const float*)resp;
    const unsigned short* resb = (const unsigned short*)resp;
    float gv[8], bev[8], bb[8];
#pragma unroll
    for (int ni = 0; ni < 8; ni++) {
        int col = wc * 128 + ni * 16 + lr;
        gv[ni] = g[col]; bev[ni] = be[col]; bb[ni] = bias[col];
    }
#pragma unroll
    for (int mi = 0; mi < 4; mi++)
#pragma unroll
        for (int jj = 0; jj < 4; jj++) {
            long row = tM + wr * 64 + mi * 16 + lg * 4 + jj;
#pragma unroll
            for (int ni = 0; ni < 8; ni++) {
                int col = wc * 128 + ni * 16 + lr;
                float rv = RESBF ? bf2f(resb[row * 512 + col]) : resf[row * 512 + col];
                acc[mi][ni][jj] += bb[ni] + rv;
            }
        }
    float s2[4][4], ss2[4][4];
#pragma unroll
    for (int mi = 0; mi < 4; mi++)
#pragma unroll
        for (int jj = 0; jj < 4; jj++) {
            float s = 0.f, ss = 0.f;
#pragma unroll
            for (int ni = 0; ni < 8; ni++) {
                float v = acc[mi][ni][jj];
                s += v; ss += v * v;
            }
#pragma unroll
            for (int off = 1; off < 16; off <<= 1) {
                s  += __shfl_xor(s, off);
                ss += __shfl_xor(ss, off);
            }
            s2[mi][jj] = s; ss2[mi][jj] = ss;
        }
    __syncthreads();
    if (lr == 0) {
#pragma unroll
        for (int mi = 0; mi < 4; mi++)
#pragma unroll
            for (int jj = 0; jj < 4; jj++) {
                int rb = wr * 64 + mi * 16 + lg * 4 + jj;
                redb[0 * 512 + wc * 128 + rb] = s2[mi][jj];
                redb[1 * 512 + wc * 128 + rb] = ss2[mi][jj];
            }
    }
    __syncthreads();
    if (t < 128) {
        float S  = redb[t] + redb[128 + t] + redb[256 + t] + redb[384 + t];
        float SS = redb[512 + t] + redb[640 + t] + redb[768 + t] + redb[896 + t];
        float mean = S * (1.0f / 512.0f);
        float var  = SS * (1.0f / 512.0f) - mean * mean;
        statb[t] = mean;
        statb[128 + t] = rsqrtf(fmaxf(var, 0.f) + 1e-5f);
    }
    __syncthreads();
#pragma unroll
    for (int h = 0; h < 2; h++) {
        if (wr == h) {
#pragma unroll
            for (int mi = 0; mi < 4; mi++)
#pragma unroll
                for (int jj = 0; jj < 4; jj++) {
                    int rb  = mi * 16 + lg * 4 + jj;
                    int rbg = h * 64 + rb;
                    long row = tM + rbg;
                    float mean = statb[rbg], rstd = statb[128 + rbg];
#pragma unroll
                    for (int ni = 0; ni < 8; ni++) {
                        int col = wc * 128 + ni * 16 + lr;
                        float y = (acc[mi][ni][jj] - mean) * rstd * gv[ni] + bev[ni];
                        if (WRITEOF) of[row * 512 + col] = y;
                        bb16[rb * 512 + (col ^ ((rb & 7) << 3))] = f2bf(y);
                    }
                }
        }
        __syncthreads();
#pragma unroll
        for (int i = 0; i < 8; i++) {
            int q = i * 512 + t;
            int r = q >> 6, cc = q & 63;
            short8 v8 = *(const short8*)&bb16[r * 512 + ((cc ^ (r & 7)) << 3)];
            *(short8*)&ob[(tM + h * 64 + r) * 512 + cc * 8] = v8;
        }
        __syncthreads();
    }
}

// ---------------------------------------------------------------------------
// Attention glue. KVbuf[(s*8+b)][1024]: cols 0..511 = phiK (later ATTN),
// cols 512..1023 = V. phiQ in QBUF (stride 512, d_out scratch).
// ctx_partial also accumulates ksum_d = sum_s phiK[s][d] (part2).
// ---------------------------------------------------------------------------
__global__ __launch_bounds__(256) void ctx_partial_kernel(
    const unsigned short* __restrict__ kv, float* __restrict__ part,
    float* __restrict__ part2)
{
    const int p = blockIdx.x, ch = blockIdx.y;
    const int b = p >> 3, h = p & 7;
    __shared__ float kb[64 * 68];
    __shared__ float vbuf[64 * 68];
    const int t = threadIdx.x;
    const int dq = t >> 4, eq = t & 15;
    f32x4 acc[4];
    f32x4 ks = {0.f, 0.f, 0.f, 0.f};
#pragma unroll
    for (int i = 0; i < 4; i++) acc[i] = f32x4{0.f, 0.f, 0.f, 0.f};

    for (int sub = 0; sub < 8; sub++) {
        int sbase = ch * 512 + sub * 64;
#pragma unroll
        for (int i = 0; i < 2; i++) {
            int idx = i * 256 + t;
            int row = idx >> 3, c8 = idx & 7;
            long ga = ((long)(sbase + row) * 8 + b) * 1024 + h * 64 + c8 * 8;
            short8 kvv = *(const short8*)&kv[ga];
            short8 vv  = *(const short8*)&kv[ga + 512];
#pragma unroll
            for (int j = 0; j < 8; j++) {
                kb[row * 68 + c8 * 8 + j]   = bf2f((unsigned short)kvv[j]);
                vbuf[row * 68 + c8 * 8 + j] = bf2f((unsigned short)vv[j]);
            }
        }
        __syncthreads();
        for (int s = 0; s < 64; s++) {
            f32x4 k4 = *(const f32x4*)&kb[s * 68 + dq * 4];
            f32x4 v4 = *(const f32x4*)&vbuf[s * 68 + eq * 4];
#pragma unroll
            for (int i = 0; i < 4; i++) acc[i] += k4[i] * v4;
            ks += k4;
        }
        __syncthreads();
    }
    float* o = part + (long)(p * 8 + ch) * 4096;
#pragma unroll
    for (int i = 0; i < 4; i++)
        *(f32x4*)&o[(dq * 4 + i) * 64 + eq * 4] = acc[i];
    if (eq == 0)
        *(f32x4*)&part2[(p * 8 + ch) * 64 + dq * 4] = ks;
}

__global__ __launch_bounds__(256) void ctx_reduce_kernel(
    const float* __restrict__ part, const float* __restrict__ part2,
    unsigned short* __restrict__ ctxA)
{
    int o = (blockIdx.x * 256 + threadIdx.x) * 4;
    int p = o >> 12, d = (o >> 6) & 63, e0 = o & 63;
    f32x4 s = {0.f, 0.f, 0.f, 0.f};
    for (int ch = 0; ch < 8; ch++)
        s += *(const f32x4*)&part[(long)(p * 8 + ch) * 4096 + d * 64 + e0];
#pragma unroll
    for (int j = 0; j < 4; j++) ctxA[p * 5120 + (e0 + j) * 64 + d] = f2bf(s[j]);
    if (e0 == 0) {
        float ksv = 0.f;
#pragma unroll
        for (int ch = 0; ch < 8; ch++) ksv += part2[(p * 8 + ch) * 64 + d];
        ctxA[p * 5120 + 4096 + d] = f2bf(ksv);
#pragma unroll
        for (int j = 1; j < 16; j++) ctxA[p * 5120 + 4096 + j * 64 + d] = 0;
    }
}

// out = phiQ @ [ctx | ksum]; ni=4 accumulates denominator; normalize -> bf16.
__global__ __launch_bounds__(256) void attn_out_kernel(
    unsigned short* __restrict__ kv,
    const unsigned short* __restrict__ qbuf,
    const unsigned short* __restrict__ ctxA)
{
    __shared__ unsigned short abuf[256 * 68];
    const int p = blockIdx.x;
    const int b = p >> 3, h = p & 7;
    const int t = threadIdx.x, w = t >> 6, l = t & 63, lr = l & 15, lg = l >> 4;
    const int s0 = blockIdx.y * 256 + w * 64;
    f32x4 acc[4][5];
#pragma unroll
    for (int i = 0; i < 4; i++)
#pragma unroll
        for (int j = 0; j < 5; j++) acc[i][j] = f32x4{0.f, 0.f, 0.f, 0.f};
    const unsigned short* cb = ctxA + p * 5120;
#pragma unroll
    for (int kk = 0; kk < 2; kk++) {
        short8 af[4], bfv[5];
#pragma unroll
        for (int mi = 0; mi < 4; mi++) {
            int s = s0 + mi * 16 + lr;
            af[mi] = *(const short8*)&qbuf[((long)s * 8 + b) * 512 + h * 64 + kk * 32 + lg * 8];
        }
#pragma unroll
        for (int ni = 0; ni < 5; ni++)
            bfv[ni] = *(const short8*)&cb[(ni * 16 + lr) * 64 + kk * 32 + lg * 8];
#pragma unroll
        for (int mi = 0; mi < 4; mi++)
#pragma unroll
            for (int ni = 0; ni < 5; ni++)
                acc[mi][ni] = __builtin_amdgcn_mfma_f32_16x16x32_bf16(
                    af[mi], bfv[ni], acc[mi][ni], 0, 0, 0);
    }
#pragma unroll
    for (int mi = 0; mi < 4; mi++) {
#pragma unroll
        for (int j = 0; j < 4; j++) {
            float den = __shfl(acc[mi][4][j], (l & 48));
            float rc  = 1.0f / (den + 1e-6f);
            int rloc = w * 64 + mi * 16 + lg * 4 + j;
#pragma unroll
            for (int ni = 0; ni < 4; ni++)
                abuf[rloc * 68 + ni * 16 + lr] = f2bf(acc[mi][ni][j] * rc);
        }
    }
    __syncthreads();
    const int by256 = blockIdx.y * 256;
#pragma unroll
    for (int i = 0; i < 8; i++) {
        int q = i * 256 + t;
        int r = q >> 3, c8 = q & 7;
        short8 v8 = *(const short8*)&abuf[r * 68 + c8 * 8];
        long base = ((long)(by256 + r) * 8 + b) * 1024 + h * 64;
        *(short8*)&kv[base + c8 * 8] = v8;
    }
}

// ---------------------------------------------------------------------------
// small helpers
// ---------------------------------------------------------------------------
__global__ __launch_bounds__(256) void cvtbf_kernel(
    const float* __restrict__ x, unsigned short* __restrict__ y)
{
    long i = ((long)blockIdx.x * 256 + threadIdx.x) * 8;
    f32x4 a = *(const f32x4*)&x[i];
    f32x4 c = *(const f32x4*)&x[i + 4];
    short8 pk;
#pragma unroll
    for (int j = 0; j < 4; j++) { pk[j] = (short)f2bf(a[j]); pk[4 + j] = (short)f2bf(c[j]); }
    *(short8*)&y[i] = pk;
}

__global__ __launch_bounds__(256) void bcat_kernel(
    const float* __restrict__ bk, const float* __restrict__ bv,
    const float* __restrict__ bq, float* __restrict__ dst)
{
    int lyr = blockIdx.x;
    int j = blockIdx.y * 256 + threadIdx.x;
    float v;
    if (j < 512)       v = bk[lyr * 512 + j];
    else if (j < 1024) v = bv[lyr * 512 + j - 512];
    else               v = bq[lyr * 512 + j - 1024];
    dst[lyr * 1536 + j] = v;
}

__global__ __launch_bounds__(256) void wconv_kernel(
    const float* __restrict__ W, unsigned short* __restrict__ Wt, int K, int N,
    long lstrW, long lstrT)
{
    __shared__ float tile[64 * 65];
    const long lz = blockIdx.z;
    const float* Wl = W + lz * lstrW;
    unsigned short* Wtl = Wt + lz * lstrT;
    const int k0 = blockIdx.x * 64, n0 = blockIdx.y * 64;
    const int t = threadIdx.x;
#pragma unroll
    for (int i = 0; i < 4; i++) {
        int q = i * 256 + t;
        int r = q >> 4, c4 = q & 15;
        f32x4 v = *(const f32x4*)&Wl[(long)(k0 + r) * N + n0 + c4 * 4];
#pragma unroll
        for (int j = 0; j < 4; j++) tile[r * 65 + c4 * 4 + j] = v[j];
    }
    __syncthreads();
#pragma unroll
    for (int i = 0; i < 4; i++) {
        int q = i * 256 + t;
        int nr = q >> 4, kc = q & 15;
        ushort4v pk;
#pragma unroll
        for (int j = 0; j < 4; j++) pk[j] = f2bf(tile[(kc * 4 + j) * 65 + nr]);
        *(ushort4v*)&Wtl[(long)(n0 + nr) * K + k0 + kc * 4] = pk;
    }
}

// ---------------------------------------------------------------------------
// Host orchestration.  ws ~123 MiB:
//  [WKVQ 6M][WO 2M][W1 4M][W2 4M][BKVQ 24K][R1 32M][KV 64M][KSP][CTP 8M][CTA]
// Q scratch = d_out. Stream: R1 bf16 in-place hops; final LN2 -> d_out f32.
// ---------------------------------------------------------------------------
extern "C" void kernel_launch(void* const* d_in, const int* in_sizes, int n_in,
                              void* d_out, int out_size, void* d_ws, size_t ws_size,
                              hipStream_t stream)
{
    const float* src  = (const float*)d_in[0];
    const float* Wq   = (const float*)d_in[1];
    const float* bq   = (const float*)d_in[2];
    const float* Wk   = (const float*)d_in[3];
    const float* bk   = (const float*)d_in[4];
    const float* Wv   = (const float*)d_in[5];
    const float* bv   = (const float*)d_in[6];
    const float* Wo   = (const float*)d_in[7];
    const float* bo   = (const float*)d_in[8];
    const float* l1g  = (const float*)d_in[9];
    const float* l1b  = (const float*)d_in[10];
    const float* W1   = (const float*)d_in[11];
    const float* b1   = (const float*)d_in[12];
    const float* W2   = (const float*)d_in[13];
    const float* b2   = (const float*)d_in[14];
    const float* l2g  = (const float*)d_in[15];
    const float* l2b  = (const float*)d_in[16];

    char* ws = (char*)d_ws;
    constexpr size_t SZ_WKVQ = (size_t)4 * 1536 * 512 * 2;
    constexpr size_t SZ_WO   = (size_t)4 * 512 * 512 * 2;
    constexpr size_t SZ_W1   = (size_t)4 * 512 * 1024 * 2;
    constexpr size_t SZ_W2   = SZ_W1;
    constexpr size_t SZ_BKVQ = (size_t)4 * 1536 * 4;
    constexpr size_t SZ_R1   = (size_t)32768 * 512 * 2;
    constexpr size_t SZ_KV   = (size_t)32768 * 1024 * 2;
    constexpr size_t OFF_WKVQ = 0;
    constexpr size_t OFF_WO   = OFF_WKVQ + SZ_WKVQ;
    constexpr size_t OFF_W1   = OFF_WO + SZ_WO;
    constexpr size_t OFF_W2   = OFF_W1 + SZ_W1;
    constexpr size_t OFF_BKVQ = OFF_W2 + SZ_W2;
    constexpr size_t OFF_R1   = OFF_BKVQ + SZ_BKVQ;
    constexpr size_t OFF_KV   = OFF_R1 + SZ_R1;
    constexpr size_t OFF_KSP  = OFF_KV + SZ_KV;
    constexpr size_t OFF_CTP  = OFF_KSP + (size_t)16 * 4096 * 4;
    constexpr size_t OFF_CTA  = OFF_CTP + (size_t)64 * 8 * 4096 * 4;

    unsigned short* WKVQ = (unsigned short*)(ws + OFF_WKVQ);
    unsigned short* WOT  = (unsigned short*)(ws + OFF_WO);
    unsigned short* W1T  = (unsigned short*)(ws + OFF_W1);
    unsigned short* W2T  = (unsigned short*)(ws + OFF_W2);
    float*          BKVQ = (float*)(ws + OFF_BKVQ);
    unsigned short* R1   = (unsigned short*)(ws + OFF_R1);
    unsigned short* KV   = (unsigned short*)(ws + OFF_KV);
    float*          KSP  = (float*)(ws + OFF_KSP);
    float*          CTP  = (float*)(ws + OFF_CTP);
    unsigned short* CTA  = (unsigned short*)(ws + OFF_CTA);
    float*          F1   = (float*)d_out;
    unsigned short* QBUF = (unsigned short*)d_out;

    dim3 blk(256);
    wconv_kernel<<<dim3(8, 8, 4),  blk, 0, stream>>>(Wk, WKVQ,             512, 512, 512*512, 1536*512);
    wconv_kernel<<<dim3(8, 8, 4),  blk, 0, stream>>>(Wv, WKVQ + 512*512,   512, 512, 512*512, 1536*512);
    wconv_kernel<<<dim3(8, 8, 4),  blk, 0, stream>>>(Wq, WKVQ + 1024*512,  512, 512, 512*512, 1536*512);
    wconv_kernel<<<dim3(8, 8, 4),  blk, 0, stream>>>(Wo, WOT,              512, 512, 512*512, 512*512);
    wconv_kernel<<<dim3(8, 16, 4), blk, 0, stream>>>(W1, W1T,              512, 1024, 512*1024, 512*1024);
    wconv_kernel<<<dim3(16, 8, 4), blk, 0, stream>>>(W2, W2T,              1024, 512, 1024*512, 1024*512);
    bcat_kernel<<<dim3(4, 6), blk, 0, stream>>>(bk, bv, bq, BKVQ);
    cvtbf_kernel<<<8192, blk, 0, stream>>>(src, R1);

    for (int lyr = 0; lyr < 4; lyr++) {
        const unsigned short* wkvq = WKVQ + (size_t)lyr * 1536 * 512;
        const unsigned short* wot  = WOT  + (size_t)lyr * 512 * 512;
        const unsigned short* w1t  = W1T  + (size_t)lyr * 512 * 1024;
        const unsigned short* w2t  = W2T  + (size_t)lyr * 1024 * 512;

        // K|V|Q fused GEMM: 128 M-tiles x 12 N-tiles = 1536 blocks
        gemm_kernel<0, 12, 512, 512><<<1536, dim3(512), 0, stream>>>(R1, wkvq, BKVQ + lyr * 1536,
                                                                     KV, 1024, QBUF);

        ctx_partial_kernel<<<dim3(64, 8), blk, 0, stream>>>(KV, CTP, KSP);
        ctx_reduce_kernel<<<256, blk, 0, stream>>>(CTP, KSP, CTA);

        attn_out_kernel<<<dim3(64, 16), blk, 0, stream>>>(KV, QBUF, CTA);

        if (lyr == 0)
            gemm_ln_kernel<0, 0, 512><<<256, dim3(512), 0, stream>>>(KV, 1024, wot, bo + lyr * 512, src,
                                                                     l1g + lyr * 512, l1b + lyr * 512,
                                                                     F1, R1, 0);
        else
            gemm_ln_kernel<1, 0, 512><<<256, dim3(512), 0, stream>>>(KV, 1024, wot, bo + lyr * 512, R1,
                                                                     l1g + lyr * 512, l1b + lyr * 512,
                                                                     F1, R1, 0);
        // FFN up: 128 M-tiles x 8 N-tiles = 1024 blocks
        gemm_kernel<2, 8, 512, 512><<<1024, dim3(512), 0, stream>>>(R1, w1t, b1 + lyr * 1024,
                                                                    KV, 1024, nullptr);
        if (lyr == 3)
            gemm_ln_kernel<1, 1, 1024><<<256, dim3(512), 0, stream>>>(KV, 1024, w2t, b2 + lyr * 512, R1,
                                                                      l2g + lyr * 512, l2b + lyr * 512,
                                                                      F1, R1, 0);
        else
            gemm_ln_kernel<1, 0, 1024><<<256, dim3(512), 0, stream>>>(KV, 1024, w2t, b2 + lyr * 512, R1,
                                                                      l2g + lyr * 512, l2b + lyr * 512,
                                                                      F1, R1, 0);
    }
}

// Round 19
// 1121.047 us; speedup vs baseline: 1.0695x; 1.0695x over previous
//
#include <hip/hip_runtime.h>
#include <hip/hip_bf16.h>
#include <cstdint>

typedef __attribute__((ext_vector_type(8))) short short8;
typedef __attribute__((ext_vector_type(4))) float f32x4;
typedef __attribute__((ext_vector_type(4))) unsigned short ushort4v;

#define DEV static __device__ __forceinline__

DEV float bf2f(unsigned short u) {
    union { unsigned int i; float f; } v; v.i = ((unsigned int)u) << 16; return v.f;
}
DEV unsigned short f2bf(float f) {
    union { float f; unsigned int i; } v; v.f = f;
    unsigned int x = v.i;
    unsigned int r = x + 0x7fffu + ((x >> 16) & 1u);
    return (unsigned short)(r >> 16);
}

// ---------------------------------------------------------------------------
// GEMM: C[M,N] = A[M,K] @ Bt[N,K]^T + bias -> bf16. 128x128 tile, 4 waves,
// BK=64 single-buffer (measured best: 78us KVQ; 4 blocks/CU TLP beats all
// attempted source-level pipelining at this shape). LDA/KT compile-time +
// full K-unroll + hoisted per-lane staging pointers. XCD swizzle.
// EPI 0 (KVQ): elu+1 on cols<512|>=1024; Q -> out2. EPI 2 (W1): relu.
// ---------------------------------------------------------------------------
template<int EPI, int NBY, int LDA, int KT>
__global__ __launch_bounds__(256) void gemm_kernel(
    const unsigned short* __restrict__ A,
    const unsigned short* __restrict__ Bt,
    const float* __restrict__ bias,
    unsigned short* __restrict__ out1, int ldc1,
    unsigned short* __restrict__ out2)
{
    __shared__ unsigned short lds[128 * 136];
    const int t  = threadIdx.x;
    const int w  = t >> 6, l = t & 63;
    const int wr = w >> 1, wc = w & 1;
    const int lr = l & 15, lg = l >> 4;
    const int bid = blockIdx.x;
    const int j8  = bid & 7, s = bid >> 3;
    const int bx  = j8 * 32 + s / NBY;
    const int by  = s % NBY;
    const long tM = (long)bx * 128;
    const long tN = (long)by * 128;

    f32x4 acc[4][4];
#pragma unroll
    for (int i = 0; i < 4; i++)
#pragma unroll
        for (int j = 0; j < 4; j++) acc[i][j] = f32x4{0.f, 0.f, 0.f, 0.f};

    const unsigned short* ga[4];
    const unsigned short* gb[4];
    unsigned int ldsa[4], ldsb[4];
#pragma unroll
    for (int j = 0; j < 4; j++) {
        int c = (w * 4 + j) * 64 + l;
        int row = c >> 3, sc = (c & 7) ^ (row & 7);
        ga[j] = A + (tM + row) * LDA + sc * 8;
        gb[j] = Bt + (tN + row) * (long)KT + sc * 8;
        ldsa[j] = (w * 4 + j) * 512;
        ldsb[j] = 8192 + (w * 4 + j) * 512;
    }

#pragma unroll
    for (int kt = 0; kt < KT; kt += 64) {
#pragma unroll
        for (int j = 0; j < 4; j++)
            __builtin_amdgcn_global_load_lds(
                (const __attribute__((address_space(1))) void*)(ga[j] + kt),
                (__attribute__((address_space(3))) void*)(lds + ldsa[j]), 16, 0, 0);
#pragma unroll
        for (int j = 0; j < 4; j++)
            __builtin_amdgcn_global_load_lds(
                (const __attribute__((address_space(1))) void*)(gb[j] + kt),
                (__attribute__((address_space(3))) void*)(lds + ldsb[j]), 16, 0, 0);
        __syncthreads();
#pragma unroll
        for (int kk = 0; kk < 2; kk++) {
            short8 af[4], bfv[4];
#pragma unroll
            for (int mi = 0; mi < 4; mi++) {
                int r  = wr * 64 + mi * 16 + lr;
                int kc = kk * 4 + lg;
                af[mi] = *(const short8*)&lds[r * 64 + ((kc ^ (r & 7)) << 3)];
            }
#pragma unroll
            for (int ni = 0; ni < 4; ni++) {
                int n  = wc * 64 + ni * 16 + lr;
                int kc = kk * 4 + lg;
                bfv[ni] = *(const short8*)&lds[8192 + n * 64 + ((kc ^ (n & 7)) << 3)];
            }
#pragma unroll
            for (int mi = 0; mi < 4; mi++)
#pragma unroll
                for (int ni = 0; ni < 4; ni++)
                    acc[mi][ni] = __builtin_amdgcn_mfma_f32_16x16x32_bf16(
                        af[mi], bfv[ni], acc[mi][ni], 0, 0, 0);
        }
        __syncthreads();
    }

    float bv[4];
#pragma unroll
    for (int ni = 0; ni < 4; ni++) bv[ni] = bias[tN + wc * 64 + ni * 16 + lr];
    const bool doElu = (EPI == 0) && (tN < 512 || tN >= 1024);

#pragma unroll
    for (int mi = 0; mi < 4; mi++)
#pragma unroll
        for (int ni = 0; ni < 4; ni++)
#pragma unroll
            for (int j = 0; j < 4; j++) {
                float v = acc[mi][ni][j] + bv[ni];
                if (EPI == 0) { if (doElu) v = (v > 0.f) ? (v + 1.f) : expf(v); }
                if (EPI == 2) v = fmaxf(v, 0.f);
                int r = wr * 64 + mi * 16 + lg * 4 + j;
                int c = wc * 64 + ni * 16 + lr;
                lds[r * 136 + c] = f2bf(v);
            }
    __syncthreads();
    const bool toQ = (NBY == 12) && (tN >= 1024);
    unsigned short* o = toQ ? out2 : out1;
    const long ldc   = toQ ? 512 : ldc1;
    const long cb    = toQ ? (tN - 1024) : tN;
#pragma unroll
    for (int i = 0; i < 8; i++) {
        int q = i * 256 + t;
        int r = q >> 4, cc = q & 15;
        short8 v8 = *(const short8*)&lds[r * 136 + cc * 8];
        *(short8*)&o[(tM + r) * ldc + cb + cc * 8] = v8;
    }
}

// ---------------------------------------------------------------------------
// Fused GEMM + bias + residual + LayerNorm, 2-phase dbuf BK=32 (r10-r14
// proven), KT compile-time + full unroll + hoisted staging pointers.
// RESBF: residual bf16 vs f32 (src, layer 0). WRITEOF: final LN2 -> d_out.
// NO min-wave bound (r8: forced cap -> accumulator spill).
// ---------------------------------------------------------------------------
template<int RESBF, int WRITEOF, int KT>
__global__ __launch_bounds__(512) void gemm_ln_kernel(
    const unsigned short* __restrict__ A, int lda,
    const unsigned short* __restrict__ Bt,   // [512][KT]
    const float* __restrict__ bias,          // [512]
    const void* __restrict__ resp,           // [M][512] f32 or bf16 (RESBF)
    const float* __restrict__ g,
    const float* __restrict__ be,
    float* __restrict__ of,                  // [M][512] f32 (if WRITEOF)
    unsigned short* __restrict__ ob,         // [M][512] bf16
    int unused)
{
    __shared__ unsigned short sA[2][128 * 32];   // 2 x 8 KiB
    __shared__ unsigned short sB[2][512 * 32];   // 2 x 32 KiB
    float* redb  = (float*)&sA[0][0];            // epilogue alias: 4 KiB
    float* statb = redb + 1024;                  // 1 KiB
    const int t = threadIdx.x, w = t >> 6, l = t & 63, lr = l & 15, lg = l >> 4;
    const int wr = w >> 2, wc = w & 3;
    const long tM = (long)blockIdx.x * 128;

    f32x4 acc[4][8];
#pragma unroll
    for (int i = 0; i < 4; i++)
#pragma unroll
        for (int j = 0; j < 8; j++) acc[i][j] = f32x4{0.f, 0.f, 0.f, 0.f};

    // hoisted staging pointers
    const unsigned short* gA;
    const unsigned short* gB[4];
    unsigned int la, lb[4];
    {
        int c = t, row = c >> 2, sc = (c & 3) ^ ((row >> 1) & 3);
        gA = A + (tM + row) * (long)lda + sc * 8;
        la = (w * 64) * 8;
    }
#pragma unroll
    for (int j = 0; j < 4; j++) {
        int c = j * 512 + t, row = c >> 2, sc = (c & 3) ^ ((row >> 1) & 3);
        gB[j] = Bt + (long)row * KT + sc * 8;
        lb[j] = (j * 512 + w * 64) * 8;
    }

    auto STAGE = [&](int buf, int kt) {
        __builtin_amdgcn_global_load_lds(
            (const __attribute__((address_space(1))) void*)(gA + kt),
            (__attribute__((address_space(3))) void*)(&sA[buf][la]), 16, 0, 0);
#pragma unroll
        for (int j = 0; j < 4; j++)
            __builtin_amdgcn_global_load_lds(
                (const __attribute__((address_space(1))) void*)(gB[j] + kt),
                (__attribute__((address_space(3))) void*)(&sB[buf][lb[j]]), 16, 0, 0);
    };

    auto COMPUTE = [&](int buf) {
        short8 av[4], bw[8];
#pragma unroll
        for (int mi = 0; mi < 4; mi++) {
            int r = wr * 64 + mi * 16 + lr;
            av[mi] = *(const short8*)&sA[buf][r * 32 + ((lg ^ ((r >> 1) & 3)) << 3)];
        }
#pragma unroll
        for (int ni = 0; ni < 8; ni++) {
            int n = wc * 128 + ni * 16 + lr;
            bw[ni] = *(const short8*)&sB[buf][n * 32 + ((lg ^ ((n >> 1) & 3)) << 3)];
        }
#pragma unroll
        for (int mi = 0; mi < 4; mi++)
#pragma unroll
            for (int ni = 0; ni < 8; ni++)
                acc[mi][ni] = __builtin_amdgcn_mfma_f32_16x16x32_bf16(
                    av[mi], bw[ni], acc[mi][ni], 0, 0, 0);
    };

    STAGE(0, 0);
    __syncthreads();
#pragma unroll
    for (int kt = 32; kt < KT; kt += 32) {
        const int cur = ((kt >> 5) & 1) ^ 1;   // compile-time per unrolled iter
        STAGE(cur ^ 1, kt);
        COMPUTE(cur);
        __syncthreads();
    }
    COMPUTE(((KT >> 5) & 1) ^ 1);

    const float* resf = (const float*)resp;
    const unsigned short* resb = (const unsigned short*)resp;
    float gv[8], bev[8], bb[8];
#pragma unroll
    for (int ni = 0; ni < 8; ni++) {
        int col = wc * 128 + ni * 16 + lr;
        gv[ni] = g[col]; bev[ni] = be[col]; bb[ni] = bias[col];
    }
#pragma unroll
    for (int mi = 0; mi < 4; mi++)
#pragma unroll
        for (int jj = 0; jj < 4; jj++) {
            long row = tM + wr * 64 + mi * 16 + lg * 4 + jj;
#pragma unroll
            for (int ni = 0; ni < 8; ni++) {
                int col = wc * 128 + ni * 16 + lr;
                float rv = RESBF ? bf2f(resb[row * 512 + col]) : resf[row * 512 + col];
                acc[mi][ni][jj] += bb[ni] + rv;
            }
        }
    float s2[4][4], ss2[4][4];
#pragma unroll
    for (int mi = 0; mi < 4; mi++)
#pragma unroll
        for (int jj = 0; jj < 4; jj++) {
            float s = 0.f, ss = 0.f;
#pragma unroll
            for (int ni = 0; ni < 8; ni++) {
                float v = acc[mi][ni][jj];
                s += v; ss += v * v;
            }
#pragma unroll
            for (int off = 1; off < 16; off <<= 1) {
                s  += __shfl_xor(s, off);
                ss += __shfl_xor(ss, off);
            }
            s2[mi][jj] = s; ss2[mi][jj] = ss;
        }
    __syncthreads();
    if (lr == 0) {
#pragma unroll
        for (int mi = 0; mi < 4; mi++)
#pragma unroll
            for (int jj = 0; jj < 4; jj++) {
                int rb = wr * 64 + mi * 16 + lg * 4 + jj;
                redb[0 * 512 + wc * 128 + rb] = s2[mi][jj];
                redb[1 * 512 + wc * 128 + rb] = ss2[mi][jj];
            }
    }
    __syncthreads();
    if (t < 128) {
        float S  = redb[t] + redb[128 + t] + redb[256 + t] + redb[384 + t];
        float SS = redb[512 + t] + redb[640 + t] + redb[768 + t] + redb[896 + t];
        float mean = S * (1.0f / 512.0f);
        float var  = SS * (1.0f / 512.0f) - mean * mean;
        statb[t] = mean;
        statb[128 + t] = rsqrtf(fmaxf(var, 0.f) + 1e-5f);
    }
    __syncthreads();
#pragma unroll
    for (int mi = 0; mi < 4; mi++)
#pragma unroll
        for (int jj = 0; jj < 4; jj++) {
            int rb = wr * 64 + mi * 16 + lg * 4 + jj;
            long row = tM + rb;
            float mean = statb[rb], rstd = statb[128 + rb];
#pragma unroll
            for (int ni = 0; ni < 8; ni++) {
                int col = wc * 128 + ni * 16 + lr;
                float y = (acc[mi][ni][jj] - mean) * rstd * gv[ni] + bev[ni];
                if (WRITEOF) of[row * 512 + col] = y;
                ob[row * 512 + col] = f2bf(y);
            }
        }
}

// ---------------------------------------------------------------------------
// Attention glue. KVbuf[(s*8+b)][1024]: cols 0..511 = phiK (later ATTN),
// cols 512..1023 = V. phiQ lives in QBUF (stride 512, d_out scratch).
// ctx_partial also accumulates ksum_d = sum_s phiK[s][d] (part2).
// ---------------------------------------------------------------------------
__global__ __launch_bounds__(256) void ctx_partial_kernel(
    const unsigned short* __restrict__ kv, float* __restrict__ part,
    float* __restrict__ part2)
{
    const int p = blockIdx.x, ch = blockIdx.y;
    const int b = p >> 3, h = p & 7;
    __shared__ float kb[64 * 68];
    __shared__ float vbuf[64 * 68];
    const int t = threadIdx.x;
    const int dq = t >> 4, eq = t & 15;
    f32x4 acc[4];
    f32x4 ks = {0.f, 0.f, 0.f, 0.f};
#pragma unroll
    for (int i = 0; i < 4; i++) acc[i] = f32x4{0.f, 0.f, 0.f, 0.f};

    for (int sub = 0; sub < 8; sub++) {
        int sbase = ch * 512 + sub * 64;
#pragma unroll
        for (int i = 0; i < 2; i++) {
            int idx = i * 256 + t;
            int row = idx >> 3, c8 = idx & 7;
            long ga = ((long)(sbase + row) * 8 + b) * 1024 + h * 64 + c8 * 8;
            short8 kvv = *(const short8*)&kv[ga];
            short8 vv  = *(const short8*)&kv[ga + 512];
#pragma unroll
            for (int j = 0; j < 8; j++) {
                kb[row * 68 + c8 * 8 + j]   = bf2f((unsigned short)kvv[j]);
                vbuf[row * 68 + c8 * 8 + j] = bf2f((unsigned short)vv[j]);
            }
        }
        __syncthreads();
        for (int s = 0; s < 64; s++) {
            f32x4 k4 = *(const f32x4*)&kb[s * 68 + dq * 4];
            f32x4 v4 = *(const f32x4*)&vbuf[s * 68 + eq * 4];
#pragma unroll
            for (int i = 0; i < 4; i++) acc[i] += k4[i] * v4;
            ks += k4;
        }
        __syncthreads();
    }
    float* o = part + (long)(p * 8 + ch) * 4096;
#pragma unroll
    for (int i = 0; i < 4; i++)
        *(f32x4*)&o[(dq * 4 + i) * 64 + eq * 4] = acc[i];
    if (eq == 0)
        *(f32x4*)&part2[(p * 8 + ch) * 64 + dq * 4] = ks;
}

// reduce ctx partials -> ctxA[p][n=e][k=d] (bf16, transposed); finalize ksum
// into row n=64, zero rows 65..79
__global__ __launch_bounds__(256) void ctx_reduce_kernel(
    const float* __restrict__ part, const float* __restrict__ part2,
    unsigned short* __restrict__ ctxA)
{
    int o = (blockIdx.x * 256 + threadIdx.x) * 4;
    int p = o >> 12, d = (o >> 6) & 63, e0 = o & 63;
    f32x4 s = {0.f, 0.f, 0.f, 0.f};
    for (int ch = 0; ch < 8; ch++)
        s += *(const f32x4*)&part[(long)(p * 8 + ch) * 4096 + d * 64 + e0];
#pragma unroll
    for (int j = 0; j < 4; j++) ctxA[p * 5120 + (e0 + j) * 64 + d] = f2bf(s[j]);
    if (e0 == 0) {
        float ksv = 0.f;
#pragma unroll
        for (int ch = 0; ch < 8; ch++) ksv += part2[(p * 8 + ch) * 64 + d];
        ctxA[p * 5120 + 4096 + d] = f2bf(ksv);
#pragma unroll
        for (int j = 1; j < 16; j++) ctxA[p * 5120 + 4096 + j * 64 + d] = 0;
    }
}

// out = phiQ @ [ctx | ksum]; ni=4 accumulates denominator; normalize -> bf16.
__global__ __launch_bounds__(256) void attn_out_kernel(
    unsigned short* __restrict__ kv,
    const unsigned short* __restrict__ qbuf,
    const unsigned short* __restrict__ ctxA)
{
    const int p = blockIdx.x;
    const int b = p >> 3, h = p & 7;
    const int t = threadIdx.x, w = t >> 6, l = t & 63, lr = l & 15, lg = l >> 4;
    const int s0 = blockIdx.y * 256 + w * 64;
    f32x4 acc[4][5];
#pragma unroll
    for (int i = 0; i < 4; i++)
#pragma unroll
        for (int j = 0; j < 5; j++) acc[i][j] = f32x4{0.f, 0.f, 0.f, 0.f};
    const unsigned short* cb = ctxA + p * 5120;
#pragma unroll
    for (int kk = 0; kk < 2; kk++) {
        short8 af[4], bfv[5];
#pragma unroll
        for (int mi = 0; mi < 4; mi++) {
            int s = s0 + mi * 16 + lr;
            af[mi] = *(const short8*)&qbuf[((long)s * 8 + b) * 512 + h * 64 + kk * 32 + lg * 8];
        }
#pragma unroll
        for (int ni = 0; ni < 5; ni++)
            bfv[ni] = *(const short8*)&cb[(ni * 16 + lr) * 64 + kk * 32 + lg * 8];
#pragma unroll
        for (int mi = 0; mi < 4; mi++)
#pragma unroll
            for (int ni = 0; ni < 5; ni++)
                acc[mi][ni] = __builtin_amdgcn_mfma_f32_16x16x32_bf16(
                    af[mi], bfv[ni], acc[mi][ni], 0, 0, 0);
    }
#pragma unroll
    for (int mi = 0; mi < 4; mi++) {
#pragma unroll
        for (int j = 0; j < 4; j++) {
            float den = __shfl(acc[mi][4][j], (l & 48));
            float rc  = 1.0f / (den + 1e-6f);
            int s = s0 + mi * 16 + lg * 4 + j;
            long base = ((long)s * 8 + b) * 1024 + h * 64;
#pragma unroll
            for (int ni = 0; ni < 4; ni++)
                kv[base + ni * 16 + lr] = f2bf(acc[mi][ni][j] * rc);
        }
    }
}

// ---------------------------------------------------------------------------
// small helpers
// ---------------------------------------------------------------------------
__global__ __launch_bounds__(256) void cvtbf_kernel(
    const float* __restrict__ x, unsigned short* __restrict__ y)
{
    long i = ((long)blockIdx.x * 256 + threadIdx.x) * 8;
    f32x4 a = *(const f32x4*)&x[i];
    f32x4 c = *(const f32x4*)&x[i + 4];
    short8 pk;
#pragma unroll
    for (int j = 0; j < 4; j++) { pk[j] = (short)f2bf(a[j]); pk[4 + j] = (short)f2bf(c[j]); }
    *(short8*)&y[i] = pk;
}

// concat biases: dst[lyr][1536] = bk | bv | bq
__global__ __launch_bounds__(256) void bcat_kernel(
    const float* __restrict__ bk, const float* __restrict__ bv,
    const float* __restrict__ bq, float* __restrict__ dst)
{
    int lyr = blockIdx.x;
    int j = blockIdx.y * 256 + threadIdx.x;  // 0..1535
    float v;
    if (j < 512)       v = bk[lyr * 512 + j];
    else if (j < 1024) v = bv[lyr * 512 + j - 512];
    else               v = bq[lyr * 512 + j - 1024];
    dst[lyr * 1536 + j] = v;
}

// weight transpose + convert: Wt[n][k] = (bf16) W[k][n], per-layer strides
__global__ __launch_bounds__(256) void wconv_kernel(
    const float* __restrict__ W, unsigned short* __restrict__ Wt, int K, int N,
    long lstrW, long lstrT)
{
    __shared__ float tile[64 * 65];
    const long lz = blockIdx.z;
    const float* Wl = W + lz * lstrW;
    unsigned short* Wtl = Wt + lz * lstrT;
    const int k0 = blockIdx.x * 64, n0 = blockIdx.y * 64;
    const int t = threadIdx.x;
#pragma unroll
    for (int i = 0; i < 4; i++) {
        int q = i * 256 + t;
        int r = q >> 4, c4 = q & 15;
        f32x4 v = *(const f32x4*)&Wl[(long)(k0 + r) * N + n0 + c4 * 4];
#pragma unroll
        for (int j = 0; j < 4; j++) tile[r * 65 + c4 * 4 + j] = v[j];
    }
    __syncthreads();
#pragma unroll
    for (int i = 0; i < 4; i++) {
        int q = i * 256 + t;
        int nr = q >> 4, kc = q & 15;
        ushort4v pk;
#pragma unroll
        for (int j = 0; j < 4; j++) pk[j] = f2bf(tile[(kc * 4 + j) * 65 + nr]);
        *(ushort4v*)&Wtl[(long)(n0 + nr) * K + k0 + kc * 4] = pk;
    }
}

// ---------------------------------------------------------------------------
// Host orchestration.  ws ~123 MiB:
//  [WKVQ 6M][WO 2M][W1 4M][W2 4M][BKVQ 24K][R1 32M][KV 64M][KSP][CTP 8M][CTA]
// Q scratch = d_out (bf16 reinterp; only final LN2 writes d_out f32, after
// the last attn_out consumed Q). Stream: R1 bf16 in-place hops.
// ---------------------------------------------------------------------------
extern "C" void kernel_launch(void* const* d_in, const int* in_sizes, int n_in,
                              void* d_out, int out_size, void* d_ws, size_t ws_size,
                              hipStream_t stream)
{
    const float* src  = (const float*)d_in[0];
    const float* Wq   = (const float*)d_in[1];
    const float* bq   = (const float*)d_in[2];
    const float* Wk   = (const float*)d_in[3];
    const float* bk   = (const float*)d_in[4];
    const float* Wv   = (const float*)d_in[5];
    const float* bv   = (const float*)d_in[6];
    const float* Wo   = (const float*)d_in[7];
    const float* bo   = (const float*)d_in[8];
    const float* l1g  = (const float*)d_in[9];
    const float* l1b  = (const float*)d_in[10];
    const float* W1   = (const float*)d_in[11];
    const float* b1   = (const float*)d_in[12];
    const float* W2   = (const float*)d_in[13];
    const float* b2   = (const float*)d_in[14];
    const float* l2g  = (const float*)d_in[15];
    const float* l2b  = (const float*)d_in[16];

    char* ws = (char*)d_ws;
    constexpr size_t SZ_WKVQ = (size_t)4 * 1536 * 512 * 2;   // 6 MiB
    constexpr size_t SZ_WO   = (size_t)4 * 512 * 512 * 2;
    constexpr size_t SZ_W1   = (size_t)4 * 512 * 1024 * 2;
    constexpr size_t SZ_W2   = SZ_W1;
    constexpr size_t SZ_BKVQ = (size_t)4 * 1536 * 4;
    constexpr size_t SZ_R1   = (size_t)32768 * 512 * 2;
    constexpr size_t SZ_KV   = (size_t)32768 * 1024 * 2;
    constexpr size_t OFF_WKVQ = 0;
    constexpr size_t OFF_WO   = OFF_WKVQ + SZ_WKVQ;
    constexpr size_t OFF_W1   = OFF_WO + SZ_WO;
    constexpr size_t OFF_W2   = OFF_W1 + SZ_W1;
    constexpr size_t OFF_BKVQ = OFF_W2 + SZ_W2;
    constexpr size_t OFF_R1   = OFF_BKVQ + SZ_BKVQ;
    constexpr size_t OFF_KV   = OFF_R1 + SZ_R1;
    constexpr size_t OFF_KSP  = OFF_KV + SZ_KV;
    constexpr size_t OFF_CTP  = OFF_KSP + (size_t)16 * 4096 * 4;
    constexpr size_t OFF_CTA  = OFF_CTP + (size_t)64 * 8 * 4096 * 4;

    unsigned short* WKVQ = (unsigned short*)(ws + OFF_WKVQ);
    unsigned short* WOT  = (unsigned short*)(ws + OFF_WO);
    unsigned short* W1T  = (unsigned short*)(ws + OFF_W1);
    unsigned short* W2T  = (unsigned short*)(ws + OFF_W2);
    float*          BKVQ = (float*)(ws + OFF_BKVQ);
    unsigned short* R1   = (unsigned short*)(ws + OFF_R1);
    unsigned short* KV   = (unsigned short*)(ws + OFF_KV);
    float*          KSP  = (float*)(ws + OFF_KSP);
    float*          CTP  = (float*)(ws + OFF_CTP);
    unsigned short* CTA  = (unsigned short*)(ws + OFF_CTA);
    float*          F1   = (float*)d_out;                     // final f32 out
    unsigned short* QBUF = (unsigned short*)d_out;            // Q scratch

    dim3 blk(256);
    wconv_kernel<<<dim3(8, 8, 4),  blk, 0, stream>>>(Wk, WKVQ,             512, 512, 512*512, 1536*512);
    wconv_kernel<<<dim3(8, 8, 4),  blk, 0, stream>>>(Wv, WKVQ + 512*512,   512, 512, 512*512, 1536*512);
    wconv_kernel<<<dim3(8, 8, 4),  blk, 0, stream>>>(Wq, WKVQ + 1024*512,  512, 512, 512*512, 1536*512);
    wconv_kernel<<<dim3(8, 8, 4),  blk, 0, stream>>>(Wo, WOT,              512, 512, 512*512, 512*512);
    wconv_kernel<<<dim3(8, 16, 4), blk, 0, stream>>>(W1, W1T,              512, 1024, 512*1024, 512*1024);
    wconv_kernel<<<dim3(16, 8, 4), blk, 0, stream>>>(W2, W2T,              1024, 512, 1024*512, 1024*512);
    bcat_kernel<<<dim3(4, 6), blk, 0, stream>>>(bk, bv, bq, BKVQ);
    cvtbf_kernel<<<8192, blk, 0, stream>>>(src, R1);

    for (int lyr = 0; lyr < 4; lyr++) {
        const unsigned short* wkvq = WKVQ + (size_t)lyr * 1536 * 512;
        const unsigned short* wot  = WOT  + (size_t)lyr * 512 * 512;
        const unsigned short* w1t  = W1T  + (size_t)lyr * 512 * 1024;
        const unsigned short* w2t  = W2T  + (size_t)lyr * 1024 * 512;

        // K|V|Q fused GEMM; K|V -> KV (ldc 1024), Q -> QBUF (stride 512)
        gemm_kernel<0, 12, 512, 512><<<3072, blk, 0, stream>>>(R1, wkvq, BKVQ + lyr * 1536,
                                                               KV, 1024, QBUF);

        // ctx + ksum in one pass over KV
        ctx_partial_kernel<<<dim3(64, 8), blk, 0, stream>>>(KV, CTP, KSP);
        ctx_reduce_kernel<<<256, blk, 0, stream>>>(CTP, KSP, CTA);

        // attn: Q from QBUF; ATTN into KV cols 0..511 (K slot, dead)
        attn_out_kernel<<<dim3(64, 16), blk, 0, stream>>>(KV, QBUF, CTA);

        // Wo + residual + LN1 -> bf16 R1 (in-place RMW on R1)
        if (lyr == 0)
            gemm_ln_kernel<0, 0, 512><<<256, dim3(512), 0, stream>>>(KV, 1024, wot, bo + lyr * 512, src,
                                                                     l1g + lyr * 512, l1b + lyr * 512,
                                                                     F1, R1, 0);
        else
            gemm_ln_kernel<1, 0, 512><<<256, dim3(512), 0, stream>>>(KV, 1024, wot, bo + lyr * 512, R1,
                                                                     l1g + lyr * 512, l1b + lyr * 512,
                                                                     F1, R1, 0);
        // FFN up + relu -> HBF (KV region, dead)
        gemm_kernel<2, 8, 512, 512><<<2048, blk, 0, stream>>>(R1, w1t, b1 + lyr * 1024,
                                                              KV, 1024, nullptr);
        // FFN down + residual(R1 bf16) + LN2 -> R1 bf16; final also f32 d_out
        if (lyr == 3)
            gemm_ln_kernel<1, 1, 1024><<<256, dim3(512), 0, stream>>>(KV, 1024, w2t, b2 + lyr * 512, R1,
                                                                      l2g + lyr * 512, l2b + lyr * 512,
                                                                      F1, R1, 0);
        else
            gemm_ln_kernel<1, 0, 1024><<<256, dim3(512), 0, stream>>>(KV, 1024, w2t, b2 + lyr * 512, R1,
                                                                      l2g + lyr * 512, l2b + lyr * 512,
                                                                      F1, R1, 0);
    }
}